// Round 2
// baseline (227.545 us; speedup 1.0000x reference)
//
#include <hip/hip_runtime.h>
#include <stdint.h>

#define BATCH 1024
#define DIM 768

typedef unsigned long long u64;
typedef __attribute__((ext_vector_type(8))) short short8;  // 8 bf16 = 4 VGPRs
typedef __attribute__((ext_vector_type(4))) float f32x4;

// Workspace layout (bytes):
//   [0]      u64   hashes[1024]        (8 KB)
//   [8192]   int   done; int tailcnt   (zeroed by 8B hipMemsetAsync each iter)
//   [12288]  float pmax[1024*4]        (16 KB)  per-row per-chunk max
//   [28672]  float psum[1024*4]        (16 KB)  per-row per-chunk sumexp
//   [45056]  float lval[1024]          (4 KB)   exact fp32 label logit per row
//   [49152]  ushort txtB[1024*768]     (1.5 MB) bf16, MFMA B-frag order
// B-frag order: off(col,k) = ((k>>5)*64 + (col>>4))*512 + ((k>>3)&3)*128
//                            + (col&15)*8 + (k&7)
#define WS_DONE  8192
#define WS_TAIL  8196
#define WS_PMAX 12288
#define WS_PSUM 28672
#define WS_LVAL 45056
#define WS_TXTB 49152

__device__ __forceinline__ unsigned short to_bf16(float x) {
    unsigned int u = __float_as_uint(x);
    return (unsigned short)((u + 0x7FFFu + ((u >> 16) & 1u)) >> 16);  // RNE
}

// ---------------------------------------------------------------------------
// Single fused kernel. 256 blocks x 1024 threads, 2 blocks/CU capacity
// (16 waves, 41 KB LDS) => all 256 blocks co-resident => grid flag-wait is
// deadlock-free.
//
// Phase P (pre-barrier, per block b):
//   - all 16 waves: stage A (img rows r0..r0+15 -> bf16 frag order in LDS)
//   - waves 0..5 : txt fp32 -> bf16 B-frag groups G = b*6 + wave (same
//                  group set / same math as the old prep_kernel)
//   - waves 6..9 : hash img row b*4 + (wave-6)   (bit-identical hash)
// Publish: __threadfence (release, all writers) -> __syncthreads -> tid0
// atomicAdd(done). Wait: tid0 relaxed-polls done==gridDim with s_sleep ->
// __syncthreads -> __threadfence (acquire / cache-inv).
//
// Phase G: identical to round-1 gemm_fused (MFMA k-loop, softmax partials,
// label scan + exact fp32 label logit, last-block combine via tailcnt).
// ---------------------------------------------------------------------------
__global__ __launch_bounds__(1024) void fused_kernel(
        const float* __restrict__ img, const float* __restrict__ txt,
        const float* __restrict__ scale_p, u64* __restrict__ hashes,
        unsigned short* __restrict__ txtB,
        float* __restrict__ pmax, float* __restrict__ psum,
        float* __restrict__ lval, int* __restrict__ done,
        int* __restrict__ tailcnt, float* __restrict__ out) {
    __shared__ unsigned short Ahi[16 * DIM];   // 24 KB, A-frag order
    __shared__ float logitsS[16 * 260];        // 16.6 KB (+4 pad vs bank stride)
    __shared__ int isLast;
    __shared__ float part[16];

    const int tid  = threadIdx.x;
    const int wave = tid >> 6;
    const int lane = tid & 63;
    const int quad = lane >> 4;
    const int l15  = lane & 15;
    const int r0    = (blockIdx.x >> 2) * 16;
    const int chunk = blockIdx.x & 3;

    // ---- Phase P ----------------------------------------------------------
    // stage A: wave w converts img row r0+w into frag order (block-local LDS)
    {
        const float* ir = img + (size_t)(r0 + wave) * DIM;
#pragma unroll
        for (int j = 0; j < 12; ++j) {
            const int k = lane + j * 64;
            Ahi[((k >> 3) * 16 + wave) * 8 + (k & 7)] = to_bf16(ir[k]);
        }
    }

    // txt fp32 -> bf16 B-frag order: waves 0..5, one group each
    if (wave < 6) {
        const int G  = blockIdx.x * 6 + wave;
        const int tt = G / 24;        // col-tile 0..63
        const int g  = G - tt * 24;   // k-group 0..23
        const int col = tt * 16 + l15;
        const int k0  = g * 32 + quad * 8;
        const float4 va = *(const float4*)(txt + (size_t)col * DIM + k0);
        const float4 vb = *(const float4*)(txt + (size_t)col * DIM + k0 + 4);
        short8 hv = {(short)to_bf16(va.x), (short)to_bf16(va.y),
                     (short)to_bf16(va.z), (short)to_bf16(va.w),
                     (short)to_bf16(vb.x), (short)to_bf16(vb.y),
                     (short)to_bf16(vb.z), (short)to_bf16(vb.w)};
        *(short8*)(txtB + (size_t)(g * 64 + tt) * 512 + lane * 8) = hv;
    }

    // img row hash: waves 6..9 -> rows blockIdx*4 + 0..3 (identical math)
    if (wave >= 6 && wave < 10) {
        const int row = blockIdx.x * 4 + (wave - 6);
        const float4* rp = (const float4*)(img + (size_t)row * DIM);
        u64 h = 0;
#pragma unroll
        for (int c = 0; c < 3; ++c) {
            float4 v = rp[c * 64 + lane];
            int p = c * 256 + lane * 4;
            h += ((u64)__float_as_uint(v.x) + 0x9E3779B97F4A7C15ULL) * (u64)(2 * p + 1);
            h += ((u64)__float_as_uint(v.y) + 0x9E3779B97F4A7C15ULL) * (u64)(2 * p + 3);
            h += ((u64)__float_as_uint(v.z) + 0x9E3779B97F4A7C15ULL) * (u64)(2 * p + 5);
            h += ((u64)__float_as_uint(v.w) + 0x9E3779B97F4A7C15ULL) * (u64)(2 * p + 7);
        }
#pragma unroll
        for (int m = 32; m; m >>= 1) h += __shfl_xor(h, m, 64);
        if (lane == 0) hashes[row] = h;
    }

    // ---- grid-wide publish + wait ----------------------------------------
    __threadfence();               // release: every writer drains its stores
    __syncthreads();               // (also the barrier for the Ahi staging)
    if (tid == 0) {
        __hip_atomic_fetch_add(done, 1, __ATOMIC_RELEASE, __HIP_MEMORY_SCOPE_AGENT);
        while (__hip_atomic_load(done, __ATOMIC_RELAXED, __HIP_MEMORY_SCOPE_AGENT)
               < (int)gridDim.x)
            __builtin_amdgcn_s_sleep(8);
    }
    __syncthreads();
    __threadfence();               // acquire: invalidate caches before remote reads

    // ---- Phase G (identical to round-1 gemm_fused) ------------------------
    // k-loop: wave's global col-tile t, one MFMA per 32-k step
    const int t = chunk * 16 + wave;
    const int foff = quad * 128 + l15 * 8;
    f32x4 acc = {0.f, 0.f, 0.f, 0.f};
#pragma unroll
    for (int kk = 0; kk < 24; ++kk) {
        const short8 a = *(const short8*)&Ahi[kk * 512 + foff];
        const short8 b = *(const short8*)(txtB + (size_t)(kk * 64 + t) * 512 + foff);
        acc = __builtin_amdgcn_mfma_f32_16x16x32_bf16(a, b, acc, 0, 0, 0);
    }

    // C layout: col = l15, row = quad*4 + r  [verified, absmax 0.0]
    const float scale = scale_p[0];
#pragma unroll
    for (int r = 0; r < 4; ++r)
        logitsS[(quad * 4 + r) * 260 + wave * 16 + l15] = scale * acc[r];
    __syncthreads();

    // per-row partials: wave w = row w; 4 floats/lane over 256 cols
    {
        const float4 f = *(const float4*)&logitsS[wave * 260 + lane * 4];
        float mx = fmaxf(fmaxf(f.x, f.y), fmaxf(f.z, f.w));
#pragma unroll
        for (int s = 32; s; s >>= 1) mx = fmaxf(mx, __shfl_xor(mx, s, 64));
        float sum = __expf(f.x - mx) + __expf(f.y - mx) +
                    __expf(f.z - mx) + __expf(f.w - mx);
#pragma unroll
        for (int s = 32; s; s >>= 1) sum += __shfl_xor(sum, s, 64);
        if (lane == 0) {
            atomicExch(&pmax[(r0 + wave) * 4 + chunk], mx);
            atomicExch(&psum[(r0 + wave) * 4 + chunk], sum);
        }
    }

    // designated label work: waves 0..3 handle row j = r0 + chunk*4 + wave.
    if (wave < 4) {
        const int j = r0 + chunk * 4 + wave;
        const u64 hj = hashes[j];
        int lo = -1;
        int label = j;
        for (;;) {
            int cand = BATCH;
#pragma unroll
            for (int it = 0; it < 16; ++it) {
                const int i = lane + it * 64;          // always < 1024, in-bounds
                const u64 h = hashes[i];
                if (i < j && i > lo && h == hj) cand = min(cand, i);
            }
#pragma unroll
            for (int s = 32; s; s >>= 1) cand = min(cand, __shfl_xor(cand, s, 64));
            if (cand >= j) break;                      // no candidate -> label = j
            // exact verify rows cand vs j
            const float4* rpm = (const float4*)(img + (size_t)cand * DIM);
            const float4* rpj = (const float4*)(img + (size_t)j * DIM);
            bool eq = true;
#pragma unroll
            for (int c = 0; c < 3; ++c) {
                float4 vm = rpm[c * 64 + lane];
                float4 vj = rpj[c * 64 + lane];
                eq = eq && (vm.x == vj.x) && (vm.y == vj.y) &&
                     (vm.z == vj.z) && (vm.w == vj.w);
            }
            if (__all(eq)) { label = cand; break; }
            lo = cand;                                 // false positive: rescan above it
        }

        // exact fp32 label logit: scale * dot(img[j], txt[label])
        const float4* aj = (const float4*)(img + (size_t)j * DIM);
        const float4* bl = (const float4*)(txt + (size_t)label * DIM);
        float s = 0.0f;
#pragma unroll
        for (int c = 0; c < 3; ++c) {
            const float4 va = aj[c * 64 + lane];
            const float4 vb = bl[c * 64 + lane];
            s += va.x * vb.x + va.y * vb.y + va.z * vb.z + va.w * vb.w;
        }
#pragma unroll
        for (int m = 32; m; m >>= 1) s += __shfl_xor(s, m, 64);
        if (lane == 0) atomicExch(&lval[j], scale * s);
    }

    // last-block tail (round-1 proven pattern, counter = tailcnt)
    __syncthreads();
    if (tid == 0) {
        __threadfence();
        isLast = (atomicAdd(tailcnt, 1) == (int)gridDim.x - 1) ? 1 : 0;
    }
    __syncthreads();
    if (!isLast) return;
    __threadfence();   // acquire: invalidate local caches before reading others' data

    // thread t combines row t: lse from 4 chunk partials minus label logit
    {
        const float4 m4 = *(const float4*)&pmax[tid * 4];
        const float4 s4 = *(const float4*)&psum[tid * 4];
        const float lv = lval[tid];
        const float gmax = fmaxf(fmaxf(m4.x, m4.y), fmaxf(m4.z, m4.w));
        const float ss = s4.x * __expf(m4.x - gmax) + s4.y * __expf(m4.y - gmax)
                       + s4.z * __expf(m4.z - gmax) + s4.w * __expf(m4.w - gmax);
        float loss = gmax + __logf(ss) - lv;
#pragma unroll
        for (int m = 32; m; m >>= 1) loss += __shfl_xor(loss, m, 64);
        if (lane == 0) part[wave] = loss;
        __syncthreads();
        if (tid == 0) {
            float tot = 0.0f;
#pragma unroll
            for (int w = 0; w < 16; ++w) tot += part[w];
            out[0] = tot * (1.0f / BATCH);
        }
    }
}

extern "C" void kernel_launch(void* const* d_in, const int* in_sizes, int n_in,
                              void* d_out, int out_size, void* d_ws, size_t ws_size,
                              hipStream_t stream) {
    const float* img   = (const float*)d_in[0];
    const float* txt   = (const float*)d_in[1];
    const float* scale = (const float*)d_in[2];
    float* out = (float*)d_out;
    char* ws = (char*)d_ws;

    u64*   hashes  = (u64*)ws;
    int*   done    = (int*)(ws + WS_DONE);
    int*   tailcnt = (int*)(ws + WS_TAIL);
    float* pmax    = (float*)(ws + WS_PMAX);
    float* psum    = (float*)(ws + WS_PSUM);
    float* lval    = (float*)(ws + WS_LVAL);
    unsigned short* txtB = (unsigned short*)(ws + WS_TXTB);

    hipMemsetAsync(ws + WS_DONE, 0, 8, stream);   // zero done + tailcnt
    fused_kernel<<<256, 1024, 0, stream>>>(img, txt, scale, hashes, txtB,
                                           pmax, psum, lval, done, tailcnt, out);
}

// Round 3
// 100.515 us; speedup vs baseline: 2.2638x; 2.2638x over previous
//
#include <hip/hip_runtime.h>
#include <stdint.h>

#define BATCH 1024
#define DIM 768

typedef unsigned long long u64;
typedef __attribute__((ext_vector_type(8))) short short8;  // 8 bf16 = 4 VGPRs
typedef __attribute__((ext_vector_type(4))) float f32x4;

// Workspace layout (bytes):
//   [0]      int   tailcnt             (zeroed by 4B hipMemsetAsync each iter)
//   [4096]   float pmax[1024*4]        (16 KB)  per-row per-chunk max
//   [20480]  float psum[1024*4]        (16 KB)  per-row per-chunk sumexp
//   [36864]  float lval[1024]          (4 KB)   exact fp32 label logit per row
#define WS_TAIL     0
#define WS_PMAX  4096
#define WS_PSUM 20480
#define WS_LVAL 36864

__device__ __forceinline__ unsigned short to_bf16(float x) {
    unsigned int u = __float_as_uint(x);
    return (unsigned short)((u + 0x7FFFu + ((u >> 16) & 1u)) >> 16);  // RNE
}

// ---------------------------------------------------------------------------
// Single ordinary kernel, 256 blocks x 1024 threads. No grid barrier, no
// producer->consumer dependency across blocks except the R1-proven
// counter+threadfence last-block tail (atomicExch publish, RMW-counter
// acquire, single consumer).
//
// Block = 16 rows x 256 cols (row-group b>>2, col-chunk b&3).
//  - stage A: img rows -> bf16 frag order in LDS (unchanged from R1)
//  - k-loop: B loaded DIRECTLY from fp32 txt (2x float4/lane/kk) and
//    RNE-converted in registers. Bit-identical to the old prep+txtB path:
//    txtB[(kk*64+t)*512 + foff + e] == to_bf16(txt[(t*16+l15)*768
//                                              + kk*32 + quad*8 + e]).
//  - softmax partials: unchanged math, atomicExch publish (R1-proven)
//  - labels: waves 0..3, candidate filter = first-8-bytes float2 signature
//    (compared as FLOATS so it can never exclude a true float== match),
//    exact float== verify decides; then exact fp32 label dot (unchanged).
//  - last-block tail combines (unchanged).
// ---------------------------------------------------------------------------
__global__ __launch_bounds__(1024) void fused_kernel(
        const float* __restrict__ img, const float* __restrict__ txt,
        const float* __restrict__ scale_p,
        float* __restrict__ pmax, float* __restrict__ psum,
        float* __restrict__ lval, int* __restrict__ tailcnt,
        float* __restrict__ out) {
    __shared__ unsigned short Ahi[16 * DIM];   // 24 KB, A-frag order
    __shared__ float logitsS[16 * 260];        // 16.6 KB (+4 pad vs bank stride)
    __shared__ int isLast;
    __shared__ float part[16];

    const int tid  = threadIdx.x;
    const int wave = tid >> 6;
    const int lane = tid & 63;
    const int quad = lane >> 4;
    const int l15  = lane & 15;
    const int r0    = (blockIdx.x >> 2) * 16;
    const int chunk = blockIdx.x & 3;

    // stage A: wave w converts img row r0+w into frag order
    {
        const float* ir = img + (size_t)(r0 + wave) * DIM;
#pragma unroll
        for (int j = 0; j < 12; ++j) {
            const int k = lane + j * 64;
            Ahi[((k >> 3) * 16 + wave) * 8 + (k & 7)] = to_bf16(ir[k]);
        }
    }
    __syncthreads();

    // k-loop: wave's global col-tile t; B direct from fp32 txt + RNE convert
    const int t = chunk * 16 + wave;
    const int foff = quad * 128 + l15 * 8;
    const float* tp = txt + (size_t)(t * 16 + l15) * DIM + quad * 8;
    f32x4 acc = {0.f, 0.f, 0.f, 0.f};
#pragma unroll
    for (int kk = 0; kk < 24; ++kk) {
        const short8 a = *(const short8*)&Ahi[kk * 512 + foff];
        const float4 va = *(const float4*)(tp + kk * 32);
        const float4 vb = *(const float4*)(tp + kk * 32 + 4);
        const short8 b = {(short)to_bf16(va.x), (short)to_bf16(va.y),
                          (short)to_bf16(va.z), (short)to_bf16(va.w),
                          (short)to_bf16(vb.x), (short)to_bf16(vb.y),
                          (short)to_bf16(vb.z), (short)to_bf16(vb.w)};
        acc = __builtin_amdgcn_mfma_f32_16x16x32_bf16(a, b, acc, 0, 0, 0);
    }

    // C layout: col = l15, row = quad*4 + r  [verified, absmax 0.0]
    const float scale = scale_p[0];
#pragma unroll
    for (int r = 0; r < 4; ++r)
        logitsS[(quad * 4 + r) * 260 + wave * 16 + l15] = scale * acc[r];
    __syncthreads();

    // per-row partials: wave w = row w; 4 floats/lane over 256 cols
    {
        const float4 f = *(const float4*)&logitsS[wave * 260 + lane * 4];
        float mx = fmaxf(fmaxf(f.x, f.y), fmaxf(f.z, f.w));
#pragma unroll
        for (int s = 32; s; s >>= 1) mx = fmaxf(mx, __shfl_xor(mx, s, 64));
        float sum = __expf(f.x - mx) + __expf(f.y - mx) +
                    __expf(f.z - mx) + __expf(f.w - mx);
#pragma unroll
        for (int s = 32; s; s >>= 1) sum += __shfl_xor(sum, s, 64);
        if (lane == 0) {
            atomicExch(&pmax[(r0 + wave) * 4 + chunk], mx);
            atomicExch(&psum[(r0 + wave) * 4 + chunk], sum);
        }
    }

    // labels: waves 0..3 handle row j = r0 + chunk*4 + wave.
    // Filter: float2 signature at row start (float compares). Decide: exact
    // float== verify over the full row. Default label = j (diag hit).
    if (wave < 4) {
        const int j = r0 + chunk * 4 + wave;
        const float2 sj = *(const float2*)(img + (size_t)j * DIM);
        int lo = -1;
        int label = j;
        for (;;) {
            int cand = BATCH;
#pragma unroll
            for (int it = 0; it < 16; ++it) {
                const int i = lane + it * 64;          // always < 1024, in-bounds
                const float2 si = *(const float2*)(img + (size_t)i * DIM);
                if (i < j && i > lo && si.x == sj.x && si.y == sj.y)
                    cand = min(cand, i);
            }
#pragma unroll
            for (int s = 32; s; s >>= 1) cand = min(cand, __shfl_xor(cand, s, 64));
            if (cand >= j) break;                      // no candidate -> label = j
            // exact verify rows cand vs j
            const float4* rpm = (const float4*)(img + (size_t)cand * DIM);
            const float4* rpj = (const float4*)(img + (size_t)j * DIM);
            bool eq = true;
#pragma unroll
            for (int c = 0; c < 3; ++c) {
                float4 vm = rpm[c * 64 + lane];
                float4 vj = rpj[c * 64 + lane];
                eq = eq && (vm.x == vj.x) && (vm.y == vj.y) &&
                     (vm.z == vj.z) && (vm.w == vj.w);
            }
            if (__all(eq)) { label = cand; break; }
            lo = cand;                                 // false positive: rescan above it
        }

        // exact fp32 label logit: scale * dot(img[j], txt[label])
        const float4* aj = (const float4*)(img + (size_t)j * DIM);
        const float4* bl = (const float4*)(txt + (size_t)label * DIM);
        float s = 0.0f;
#pragma unroll
        for (int c = 0; c < 3; ++c) {
            const float4 va = aj[c * 64 + lane];
            const float4 vb = bl[c * 64 + lane];
            s += va.x * vb.x + va.y * vb.y + va.z * vb.z + va.w * vb.w;
        }
#pragma unroll
        for (int m = 32; m; m >>= 1) s += __shfl_xor(s, m, 64);
        if (lane == 0) atomicExch(&lval[j], scale * s);
    }

    // last-block tail (R0/R1-proven pattern)
    __syncthreads();
    if (tid == 0) {
        __threadfence();
        isLast = (atomicAdd(tailcnt, 1) == (int)gridDim.x - 1) ? 1 : 0;
    }
    __syncthreads();
    if (!isLast) return;
    __threadfence();   // acquire: invalidate local caches before reading others' data

    // thread t combines row t: lse from 4 chunk partials minus label logit
    {
        const float4 m4 = *(const float4*)&pmax[tid * 4];
        const float4 s4 = *(const float4*)&psum[tid * 4];
        const float lv = lval[tid];
        const float gmax = fmaxf(fmaxf(m4.x, m4.y), fmaxf(m4.z, m4.w));
        const float ss = s4.x * __expf(m4.x - gmax) + s4.y * __expf(m4.y - gmax)
                       + s4.z * __expf(m4.z - gmax) + s4.w * __expf(m4.w - gmax);
        float loss = gmax + __logf(ss) - lv;
#pragma unroll
        for (int m = 32; m; m >>= 1) loss += __shfl_xor(loss, m, 64);
        if (lane == 0) part[wave] = loss;
        __syncthreads();
        if (tid == 0) {
            float tot = 0.0f;
#pragma unroll
            for (int w = 0; w < 16; ++w) tot += part[w];
            out[0] = tot * (1.0f / BATCH);
        }
    }
}

extern "C" void kernel_launch(void* const* d_in, const int* in_sizes, int n_in,
                              void* d_out, int out_size, void* d_ws, size_t ws_size,
                              hipStream_t stream) {
    const float* img   = (const float*)d_in[0];
    const float* txt   = (const float*)d_in[1];
    const float* scale = (const float*)d_in[2];
    float* out = (float*)d_out;
    char* ws = (char*)d_ws;

    int*   tailcnt = (int*)(ws + WS_TAIL);
    float* pmax    = (float*)(ws + WS_PMAX);
    float* psum    = (float*)(ws + WS_PSUM);
    float* lval    = (float*)(ws + WS_LVAL);

    hipMemsetAsync(ws + WS_TAIL, 0, 4, stream);   // zero tailcnt
    fused_kernel<<<256, 1024, 0, stream>>>(img, txt, scale,
                                           pmax, psum, lval, tailcnt, out);
}

// Round 4
// 95.382 us; speedup vs baseline: 2.3856x; 1.0538x over previous
//
#include <hip/hip_runtime.h>
#include <stdint.h>

#define BATCH 1024
#define DIM 768

typedef unsigned long long u64;
typedef __attribute__((ext_vector_type(8))) short short8;  // 8 bf16 = 4 VGPRs
typedef __attribute__((ext_vector_type(4))) float f32x4;

// Workspace layout (bytes):
//   [0]      int   tailcnt             (zeroed by 4B hipMemsetAsync each iter)
//   [4096]   float pmax[1024*4]        (16 KB)  per-row per-chunk max
//   [20480]  float psum[1024*4]        (16 KB)  per-row per-chunk sumexp
//   [36864]  float lval[1024]          (4 KB)   exact fp32 label logit per row
#define WS_TAIL     0
#define WS_PMAX  4096
#define WS_PSUM 20480
#define WS_LVAL 36864

__device__ __forceinline__ unsigned short to_bf16(float x) {
    unsigned int u = __float_as_uint(x);
    return (unsigned short)((u + 0x7FFFu + ((u >> 16) & 1u)) >> 16);  // RNE
}

__device__ __forceinline__ short8 cvt8(const float4 a, const float4 b) {
    short8 r = {(short)to_bf16(a.x), (short)to_bf16(a.y),
                (short)to_bf16(a.z), (short)to_bf16(a.w),
                (short)to_bf16(b.x), (short)to_bf16(b.y),
                (short)to_bf16(b.z), (short)to_bf16(b.w)};
    return r;
}

// ---------------------------------------------------------------------------
// Single kernel, 256 blocks x 1024 threads. Block = 16 rows x 256 cols
// (row-group b>>2, col-chunk b&3).
//
//  - stage A: img rows -> bf16 frag order in LDS (unchanged, verified)
//  - k-loop: B staged per 32-k slice into double-buffered LDS in B-frag
//    order. Producer thread (c=tid>>2, sub=tid&3) writes
//      buf[(c>>4)*512 + sub*128 + (c&15)*8 + e]
//        = to_bf16(txt[(chunk*256+c)*768 + kk*32 + sub*8 + e])
//    Consumer wave w reads buf[w*512 + quad*128 + l15*8 + e] expecting
//    col = chunk*256 + w*16 + l15, k = kk*32 + quad*8 + e  -> identical map
//    (c = w*16+l15 => c>>4 = w, c&15 = l15; sub = quad). Bit-identical to
//    the verified txtB path. One barrier per step; next-step loads issued
//    pre-MFMA so L2 latency hides under ds_read+MFMA.
//  - logitsS aliases the B buffers (used only after the k-loop's barrier).
//  - softmax partials / float2-signature labels / fp32 label dot /
//    last-block tail: unchanged from R3-verified kernel.
// ---------------------------------------------------------------------------
__global__ __launch_bounds__(1024) void fused_kernel(
        const float* __restrict__ img, const float* __restrict__ txt,
        const float* __restrict__ scale_p,
        float* __restrict__ pmax, float* __restrict__ psum,
        float* __restrict__ lval, int* __restrict__ tailcnt,
        float* __restrict__ out) {
    __shared__ __align__(16) char smem[24 * 1024 + 2 * 16 * 1024];  // 56 KB
    unsigned short* Ahi = (unsigned short*)smem;                  // 24 KB
    unsigned short* Bb[2] = {(unsigned short*)(smem + 24 * 1024),  // 16 KB
                             (unsigned short*)(smem + 40 * 1024)}; // 16 KB
    float* logitsS = (float*)(smem + 24 * 1024);  // aliases Bb after k-loop
    __shared__ int isLast;
    __shared__ float part[16];

    const int tid  = threadIdx.x;
    const int wave = tid >> 6;
    const int lane = tid & 63;
    const int quad = lane >> 4;
    const int l15  = lane & 15;
    const int r0    = (blockIdx.x >> 2) * 16;
    const int chunk = blockIdx.x & 3;

    // staging addresses (constant per thread)
    const int c   = tid >> 2;   // local col 0..255
    const int sub = tid & 3;    // k-oct 0..3
    const float* sp = txt + (size_t)(chunk * 256 + c) * DIM + sub * 8;
    const int woff = (c >> 4) * 512 + sub * 128 + (c & 15) * 8;

    // stage A: wave w converts img row r0+w into frag order
    {
        const float* ir = img + (size_t)(r0 + wave) * DIM;
#pragma unroll
        for (int j = 0; j < 12; ++j) {
            const int k = lane + j * 64;
            Ahi[((k >> 3) * 16 + wave) * 8 + (k & 7)] = to_bf16(ir[k]);
        }
    }

    // stage B slice 0
    {
        const float4 va = *(const float4*)(sp);
        const float4 vb = *(const float4*)(sp + 4);
        *(short8*)(Bb[0] + woff) = cvt8(va, vb);
    }
    __syncthreads();

    // k-loop: wave w owns col-tile t = chunk*16 + w; 1 MFMA per 32-k step
    const int foff = quad * 128 + l15 * 8;
    f32x4 acc = {0.f, 0.f, 0.f, 0.f};
#pragma unroll
    for (int kk = 0; kk < 24; ++kk) {
        float4 na, nb;
        if (kk < 23) {                       // issue next-slice loads early
            na = *(const float4*)(sp + (kk + 1) * 32);
            nb = *(const float4*)(sp + (kk + 1) * 32 + 4);
        }
        const short8 a = *(const short8*)&Ahi[kk * 512 + foff];
        const short8 b = *(const short8*)&Bb[kk & 1][wave * 512 + foff];
        acc = __builtin_amdgcn_mfma_f32_16x16x32_bf16(a, b, acc, 0, 0, 0);
        if (kk < 23)
            *(short8*)(Bb[(kk + 1) & 1] + woff) = cvt8(na, nb);
        __syncthreads();
    }

    // C layout: col = l15, row = quad*4 + r  [verified, absmax 0.0]
    const float scale = scale_p[0];
#pragma unroll
    for (int r = 0; r < 4; ++r)
        logitsS[(quad * 4 + r) * 260 + wave * 16 + l15] = scale * acc[r];
    __syncthreads();

    // per-row partials: wave w = row w; 4 floats/lane over 256 cols
    {
        const float4 f = *(const float4*)&logitsS[wave * 260 + lane * 4];
        float mx = fmaxf(fmaxf(f.x, f.y), fmaxf(f.z, f.w));
#pragma unroll
        for (int s = 32; s; s >>= 1) mx = fmaxf(mx, __shfl_xor(mx, s, 64));
        float sum = __expf(f.x - mx) + __expf(f.y - mx) +
                    __expf(f.z - mx) + __expf(f.w - mx);
#pragma unroll
        for (int s = 32; s; s >>= 1) sum += __shfl_xor(sum, s, 64);
        if (lane == 0) {
            atomicExch(&pmax[(r0 + wave) * 4 + chunk], mx);
            atomicExch(&psum[(r0 + wave) * 4 + chunk], sum);
        }
    }

    // labels: waves 0..3 handle row j = r0 + chunk*4 + wave.
    // Filter: float2 signature at row start (float compares -> can never
    // exclude a true float== match). Decide: exact float== verify.
    if (wave < 4) {
        const int j = r0 + chunk * 4 + wave;
        const float2 sj = *(const float2*)(img + (size_t)j * DIM);
        int lo = -1;
        int label = j;
        for (;;) {
            int cand = BATCH;
#pragma unroll
            for (int it = 0; it < 16; ++it) {
                const int i = lane + it * 64;          // always < 1024, in-bounds
                const float2 si = *(const float2*)(img + (size_t)i * DIM);
                if (i < j && i > lo && si.x == sj.x && si.y == sj.y)
                    cand = min(cand, i);
            }
#pragma unroll
            for (int s = 32; s; s >>= 1) cand = min(cand, __shfl_xor(cand, s, 64));
            if (cand >= j) break;                      // no candidate -> label = j
            const float4* rpm = (const float4*)(img + (size_t)cand * DIM);
            const float4* rpj = (const float4*)(img + (size_t)j * DIM);
            bool eq = true;
#pragma unroll
            for (int cc = 0; cc < 3; ++cc) {
                float4 vm = rpm[cc * 64 + lane];
                float4 vj = rpj[cc * 64 + lane];
                eq = eq && (vm.x == vj.x) && (vm.y == vj.y) &&
                     (vm.z == vj.z) && (vm.w == vj.w);
            }
            if (__all(eq)) { label = cand; break; }
            lo = cand;                                 // false positive: rescan above it
        }

        // exact fp32 label logit: scale * dot(img[j], txt[label])
        const float4* aj = (const float4*)(img + (size_t)j * DIM);
        const float4* bl = (const float4*)(txt + (size_t)label * DIM);
        float s = 0.0f;
#pragma unroll
        for (int cc = 0; cc < 3; ++cc) {
            const float4 va = aj[cc * 64 + lane];
            const float4 vb = bl[cc * 64 + lane];
            s += va.x * vb.x + va.y * vb.y + va.z * vb.z + va.w * vb.w;
        }
#pragma unroll
        for (int m = 32; m; m >>= 1) s += __shfl_xor(s, m, 64);
        if (lane == 0) atomicExch(&lval[j], scale * s);
    }

    // last-block tail (R0/R1-proven pattern)
    __syncthreads();
    if (tid == 0) {
        __threadfence();
        isLast = (atomicAdd(tailcnt, 1) == (int)gridDim.x - 1) ? 1 : 0;
    }
    __syncthreads();
    if (!isLast) return;
    __threadfence();   // acquire: invalidate local caches before reading others' data

    // thread t combines row t: lse from 4 chunk partials minus label logit
    {
        const float4 m4 = *(const float4*)&pmax[tid * 4];
        const float4 s4 = *(const float4*)&psum[tid * 4];
        const float lv = lval[tid];
        const float gmax = fmaxf(fmaxf(m4.x, m4.y), fmaxf(m4.z, m4.w));
        const float ss = s4.x * __expf(m4.x - gmax) + s4.y * __expf(m4.y - gmax)
                       + s4.z * __expf(m4.z - gmax) + s4.w * __expf(m4.w - gmax);
        float loss = gmax + __logf(ss) - lv;
#pragma unroll
        for (int m = 32; m; m >>= 1) loss += __shfl_xor(loss, m, 64);
        if (lane == 0) part[wave] = loss;
        __syncthreads();
        if (tid == 0) {
            float tot = 0.0f;
#pragma unroll
            for (int w = 0; w < 16; ++w) tot += part[w];
            out[0] = tot * (1.0f / BATCH);
        }
    }
}

extern "C" void kernel_launch(void* const* d_in, const int* in_sizes, int n_in,
                              void* d_out, int out_size, void* d_ws, size_t ws_size,
                              hipStream_t stream) {
    const float* img   = (const float*)d_in[0];
    const float* txt   = (const float*)d_in[1];
    const float* scale = (const float*)d_in[2];
    float* out = (float*)d_out;
    char* ws = (char*)d_ws;

    int*   tailcnt = (int*)(ws + WS_TAIL);
    float* pmax    = (float*)(ws + WS_PMAX);
    float* psum    = (float*)(ws + WS_PSUM);
    float* lval    = (float*)(ws + WS_LVAL);

    hipMemsetAsync(ws + WS_TAIL, 0, 4, stream);   // zero tailcnt
    fused_kernel<<<256, 1024, 0, stream>>>(img, txt, scale,
                                           pmax, psum, lval, tailcnt, out);
}

// Round 5
// 89.114 us; speedup vs baseline: 2.5534x; 1.0703x over previous
//
#include <hip/hip_runtime.h>
#include <stdint.h>

#define BATCH 1024
#define DIM 768
#define MAGIC 0x9E3779B9u

typedef __attribute__((ext_vector_type(8))) short short8;   // 8 bf16 = 4 VGPRs
typedef __attribute__((ext_vector_type(4))) short short4v;  // 4 bf16 = 2 VGPRs
typedef __attribute__((ext_vector_type(4))) float f32x4;

// Workspace layout (bytes) — NO memset node; slots scheme is poison-robust:
//   [0]      u32   slots[256]          (1 KB)  block b publishes MAGIC^b
//   [4096]   float pmax[1024*4]        (16 KB) per-row per-chunk max
//   [20480]  float psum[1024*4]        (16 KB) per-row per-chunk sumexp
//   [36864]  float lval[1024]          (4 KB)  exact fp32 label logit per row
#define WS_SLOTS    0
#define WS_PMAX  4096
#define WS_PSUM 20480
#define WS_LVAL 36864

__device__ __forceinline__ unsigned short to_bf16(float x) {
    unsigned int u = __float_as_uint(x);
    return (unsigned short)((u + 0x7FFFu + ((u >> 16) & 1u)) >> 16);  // RNE
}

__device__ __forceinline__ short8 cvt8(const float4 a, const float4 b) {
    short8 r = {(short)to_bf16(a.x), (short)to_bf16(a.y),
                (short)to_bf16(a.z), (short)to_bf16(a.w),
                (short)to_bf16(b.x), (short)to_bf16(b.y),
                (short)to_bf16(b.z), (short)to_bf16(b.w)};
    return r;
}

// ---------------------------------------------------------------------------
// Single kernel, 256 blocks x 1024 threads, no extra stream nodes.
// Block = 16 rows x 256 cols (row-group b>>2, col-chunk b&3).
//
//  k-loop (depth-2 pipeline, 2 LDS buffers, 1 barrier/step):
//    step kk: issue global loads slice kk+2 -> regs
//             ds_read + MFMA slice kk from Bb[kk&1]
//             ds_write slice kk+1 (regs loaded at step kk-1) -> Bb[(kk+1)&1]
//             __syncthreads
//    The vmcnt wait before each ds_write now has a full step of slack.
//    Producer/consumer LDS mapping identical to R4 (verified bit-exact):
//      buf[(c>>4)*512 + sub*128 + (c&15)*8 + e]
//        = to_bf16(txt[(chunk*256+c)*768 + kk*32 + sub*8 + e])
//
//  Tail (counter-free): block b publishes slots[b] = MAGIC^b after a
//  threadfence+syncthreads drain (R1-proven ordering). Block 0 polls all
//  256 slots with atomicOr(p,0) RMW reads (coherent point — fixes R2's
//  stale relaxed-load spin), then threadfence + combine. A repeated-word
//  poison can match at most ONE of the 256 distinct expected values, so
//  premature release is impossible; 256 blocks on 256 CUs are all
//  resident, so the wait is deadlock-free.
// ---------------------------------------------------------------------------
__global__ __launch_bounds__(1024) void fused_kernel(
        const float* __restrict__ img, const float* __restrict__ txt,
        const float* __restrict__ scale_p,
        float* __restrict__ pmax, float* __restrict__ psum,
        float* __restrict__ lval, unsigned int* __restrict__ slots,
        float* __restrict__ out) {
    __shared__ __align__(16) char smem[24 * 1024 + 2 * 16 * 1024];  // 56 KB
    unsigned short* Ahi = (unsigned short*)smem;                   // 24 KB
    unsigned short* Bb0 = (unsigned short*)(smem + 24 * 1024);     // 16 KB
    unsigned short* Bb1 = (unsigned short*)(smem + 40 * 1024);     // 16 KB
    float* logitsS = (float*)(smem + 24 * 1024);  // aliases Bb after k-loop
    __shared__ float part[16];

    const int tid  = threadIdx.x;
    const int wave = tid >> 6;
    const int lane = tid & 63;
    const int quad = lane >> 4;
    const int l15  = lane & 15;
    const int r0    = (blockIdx.x >> 2) * 16;
    const int chunk = blockIdx.x & 3;

    // B staging addresses (constant per thread)
    const int c   = tid >> 2;   // local col 0..255
    const int sub = tid & 3;    // k-oct 0..3
    const float* sp = txt + (size_t)(chunk * 256 + c) * DIM + sub * 8;
    const int woff = (c >> 4) * 512 + sub * 128 + (c & 15) * 8;

    // prologue: issue slice-0 loads first (maximum slack)
    const float4 p0a = *(const float4*)(sp);
    const float4 p0b = *(const float4*)(sp + 4);

    // stage A: wave w converts img row r0+w into frag order (float4 loads,
    // bit-identical values/destinations to the scalar version)
    {
        const float* ir = img + (size_t)(r0 + wave) * DIM;
#pragma unroll
        for (int j = 0; j < 3; ++j) {
            const int k0 = lane * 4 + j * 256;
            const float4 v = *(const float4*)(ir + k0);
            short4v h = {(short)to_bf16(v.x), (short)to_bf16(v.y),
                         (short)to_bf16(v.z), (short)to_bf16(v.w)};
            *(short4v*)&Ahi[((k0 >> 3) * 16 + wave) * 8 + (k0 & 7)] = h;
        }
    }

    // write B slice 0; issue slice-1 loads
    *(short8*)(Bb0 + woff) = cvt8(p0a, p0b);
    float4 ra = *(const float4*)(sp + 32);
    float4 rb = *(const float4*)(sp + 36);
    __syncthreads();

    // k-loop: wave w owns col-tile t = chunk*16 + w; 1 MFMA per 32-k step
    const int foff = quad * 128 + l15 * 8;
    f32x4 acc = {0.f, 0.f, 0.f, 0.f};
#pragma unroll
    for (int kk = 0; kk < 24; ++kk) {
        float4 na, nb;
        if (kk < 22) {                       // issue slice kk+2 loads early
            na = *(const float4*)(sp + (kk + 2) * 32);
            nb = *(const float4*)(sp + (kk + 2) * 32 + 4);
        }
        const short8 a = *(const short8*)&Ahi[kk * 512 + foff];
        const short8 b = (kk & 1) ? *(const short8*)&Bb1[wave * 512 + foff]
                                  : *(const short8*)&Bb0[wave * 512 + foff];
        acc = __builtin_amdgcn_mfma_f32_16x16x32_bf16(a, b, acc, 0, 0, 0);
        if (kk < 23) {                       // write slice kk+1 (1-step-old regs)
            unsigned short* dst = ((kk + 1) & 1) ? Bb1 : Bb0;
            *(short8*)(dst + woff) = cvt8(ra, rb);
        }
        ra = na; rb = nb;
        __syncthreads();
    }

    // C layout: col = l15, row = quad*4 + r  [verified, absmax 0.0]
    const float scale = scale_p[0];
#pragma unroll
    for (int r = 0; r < 4; ++r)
        logitsS[(quad * 4 + r) * 260 + wave * 16 + l15] = scale * acc[r];
    __syncthreads();

    // per-row partials: wave w = row w; 4 floats/lane over 256 cols
    {
        const float4 f = *(const float4*)&logitsS[wave * 260 + lane * 4];
        float mx = fmaxf(fmaxf(f.x, f.y), fmaxf(f.z, f.w));
#pragma unroll
        for (int s = 32; s; s >>= 1) mx = fmaxf(mx, __shfl_xor(mx, s, 64));
        float sum = __expf(f.x - mx) + __expf(f.y - mx) +
                    __expf(f.z - mx) + __expf(f.w - mx);
#pragma unroll
        for (int s = 32; s; s >>= 1) sum += __shfl_xor(sum, s, 64);
        if (lane == 0) {
            atomicExch(&pmax[(r0 + wave) * 4 + chunk], mx);
            atomicExch(&psum[(r0 + wave) * 4 + chunk], sum);
        }
    }

    // labels: waves 0..3 handle row j = r0 + chunk*4 + wave.
    // Filter: float2 signature at row start (float compares -> can never
    // exclude a true float== match). Decide: exact float== verify.
    if (wave < 4) {
        const int j = r0 + chunk * 4 + wave;
        const float2 sj = *(const float2*)(img + (size_t)j * DIM);
        int lo = -1;
        int label = j;
        for (;;) {
            int cand = BATCH;
#pragma unroll
            for (int it = 0; it < 16; ++it) {
                const int i = lane + it * 64;          // always < 1024, in-bounds
                const float2 si = *(const float2*)(img + (size_t)i * DIM);
                if (i < j && i > lo && si.x == sj.x && si.y == sj.y)
                    cand = min(cand, i);
            }
#pragma unroll
            for (int s = 32; s; s >>= 1) cand = min(cand, __shfl_xor(cand, s, 64));
            if (cand >= j) break;                      // no candidate -> label = j
            const float4* rpm = (const float4*)(img + (size_t)cand * DIM);
            const float4* rpj = (const float4*)(img + (size_t)j * DIM);
            bool eq = true;
#pragma unroll
            for (int cc = 0; cc < 3; ++cc) {
                float4 vm = rpm[cc * 64 + lane];
                float4 vj = rpj[cc * 64 + lane];
                eq = eq && (vm.x == vj.x) && (vm.y == vj.y) &&
                     (vm.z == vj.z) && (vm.w == vj.w);
            }
            if (__all(eq)) { label = cand; break; }
            lo = cand;                                 // false positive: rescan above it
        }

        // exact fp32 label logit: scale * dot(img[j], txt[label])
        const float4* aj = (const float4*)(img + (size_t)j * DIM);
        const float4* bl = (const float4*)(txt + (size_t)label * DIM);
        float s = 0.0f;
#pragma unroll
        for (int cc = 0; cc < 3; ++cc) {
            const float4 va = aj[cc * 64 + lane];
            const float4 vb = bl[cc * 64 + lane];
            s += va.x * vb.x + va.y * vb.y + va.z * vb.z + va.w * vb.w;
        }
#pragma unroll
        for (int m = 32; m; m >>= 1) s += __shfl_xor(s, m, 64);
        if (lane == 0) atomicExch(&lval[j], scale * s);
    }

    // publish: drain block's stores (each wave drains before s_barrier),
    // then tid0 fences + slot-exch (R1-proven ordering)
    __syncthreads();
    if (tid == 0) {
        __threadfence();
        atomicExch(&slots[blockIdx.x], MAGIC ^ (unsigned int)blockIdx.x);
    }
    if (blockIdx.x != 0) return;

    // block 0: wave 0 polls all 256 slots with coherent RMW reads
    if (wave == 0) {
        for (;;) {
            int ok = 0;
#pragma unroll
            for (int it = 0; it < 4; ++it) {
                const int i = lane + it * 64;
                const unsigned int v = atomicOr(&slots[i], 0u);
                ok += (v == (MAGIC ^ (unsigned int)i)) ? 1 : 0;
            }
#pragma unroll
            for (int s = 32; s; s >>= 1) ok += __shfl_xor(ok, s, 64);
            if (ok == 256) break;
            __builtin_amdgcn_s_sleep(8);
        }
    }
    __syncthreads();
    __threadfence();   // acquire: invalidate local caches before remote reads

    // thread t combines row t: lse from 4 chunk partials minus label logit
    {
        const float4 m4 = *(const float4*)&pmax[tid * 4];
        const float4 s4 = *(const float4*)&psum[tid * 4];
        const float lv = lval[tid];
        const float gmax = fmaxf(fmaxf(m4.x, m4.y), fmaxf(m4.z, m4.w));
        const float ss = s4.x * __expf(m4.x - gmax) + s4.y * __expf(m4.y - gmax)
                       + s4.z * __expf(m4.z - gmax) + s4.w * __expf(m4.w - gmax);
        float loss = gmax + __logf(ss) - lv;
#pragma unroll
        for (int m = 32; m; m >>= 1) loss += __shfl_xor(loss, m, 64);
        if (lane == 0) part[wave] = loss;
        __syncthreads();
        if (tid == 0) {
            float tot = 0.0f;
#pragma unroll
            for (int w = 0; w < 16; ++w) tot += part[w];
            out[0] = tot * (1.0f / BATCH);
        }
    }
}

extern "C" void kernel_launch(void* const* d_in, const int* in_sizes, int n_in,
                              void* d_out, int out_size, void* d_ws, size_t ws_size,
                              hipStream_t stream) {
    const float* img   = (const float*)d_in[0];
    const float* txt   = (const float*)d_in[1];
    const float* scale = (const float*)d_in[2];
    float* out = (float*)d_out;
    char* ws = (char*)d_ws;

    unsigned int* slots = (unsigned int*)(ws + WS_SLOTS);
    float* pmax = (float*)(ws + WS_PMAX);
    float* psum = (float*)(ws + WS_PSUM);
    float* lval = (float*)(ws + WS_LVAL);

    fused_kernel<<<256, 1024, 0, stream>>>(img, txt, scale,
                                           pmax, psum, lval, slots, out);
}

// Round 7
// 77.879 us; speedup vs baseline: 2.9218x; 1.1443x over previous
//
#include <hip/hip_runtime.h>
#include <stdint.h>

#define BATCH 1024
#define DIM 768

typedef unsigned long long u64;
typedef __attribute__((ext_vector_type(8))) short short8;  // 8 bf16 = 4 VGPRs
typedef __attribute__((ext_vector_type(4))) float f32x4;

// Workspace layout (bytes):
//   [0]      int   tailcnt             (zeroed by prep block 0; kernel-boundary
//                                       ordering makes it visible to gemm)
//   [4096]   float pmax[1024*4]        (16 KB) per-row per-chunk max
//   [20480]  float psum[1024*4]        (16 KB) per-row per-chunk sumexp
//   [36864]  float lval[1024]          (4 KB)  exact fp32 label logit per row
//   [49152]  ushort txtB[1024*768]     (1.5 MB) bf16, MFMA B-frag order
// B-frag order: off(col,k) = ((k>>5)*64 + (col>>4))*512 + ((k>>3)&3)*128
//                            + (col&15)*8 + (k&7)
// -> a wave's 16x16x32 B-fragment is one contiguous 1 KB run (16 B/lane).
#define WS_TAIL     0
#define WS_PMAX  4096
#define WS_PSUM 20480
#define WS_LVAL 36864
#define WS_TXTB 49152

__device__ __forceinline__ unsigned short to_bf16(float x) {
    unsigned int u = __float_as_uint(x);
    return (unsigned short)((u + 0x7FFFu + ((u >> 16) & 1u)) >> 16);  // RNE
}

// ---------------------------------------------------------------------------
// K1: txt fp32 -> bf16 B-frag order + zero tailcnt. 256 blocks x 256 threads.
// (R1-proven structure; hash phase deleted — labels now use float2
// signatures computed in K2.)
// ---------------------------------------------------------------------------
__global__ __launch_bounds__(256) void prep_kernel(
        const float* __restrict__ txt, int* __restrict__ tailcnt,
        unsigned short* __restrict__ txtB) {
    if (blockIdx.x == 0 && threadIdx.x == 0) { *tailcnt = 0; }
    const int wave = threadIdx.x >> 6;
    const int lane = threadIdx.x & 63;

    for (int i = wave; i < 6; i += 4) {
        const int G  = blockIdx.x * 6 + i;
        const int tt = G / 24;        // col-tile 0..63
        const int g  = G - tt * 24;   // k-group 0..23
        const int col = tt * 16 + (lane & 15);
        const int k0  = g * 32 + (lane >> 4) * 8;
        const float4 va = *(const float4*)(txt + (size_t)col * DIM + k0);
        const float4 vb = *(const float4*)(txt + (size_t)col * DIM + k0 + 4);
        short8 hv = {(short)to_bf16(va.x), (short)to_bf16(va.y),
                     (short)to_bf16(va.z), (short)to_bf16(va.w),
                     (short)to_bf16(vb.x), (short)to_bf16(vb.y),
                     (short)to_bf16(vb.z), (short)to_bf16(vb.w)};
        *(short8*)(txtB + (size_t)(g * 64 + tt) * 512 + lane * 8) = hv;
    }
}

// ---------------------------------------------------------------------------
// K2: MFMA GEMM + softmax partials + labels + label logit + last-block
// combine. 256 blocks x 1024 thr. Block = 16 rows x 256 cols (row-group
// b>>2, col-chunk b&3). R1-proven body, with:
//   - labels via float2-signature scan (R3/R4/R5-proven, 3x absmax 0.0)
//   - NO per-block release __threadfence (experiment): pmax/psum/lval are
//     device-scope atomicExch (complete at the coherent point before the
//     __syncthreads' vmcnt(0) drain releases tid0), so the tailcnt RMW
//     cannot be observed before the data atomics have completed. The last
//     block keeps its acquire __threadfence. No spin loops anywhere.
// ---------------------------------------------------------------------------
__global__ __launch_bounds__(1024) void gemm_fused(
        const float* __restrict__ img, const float* __restrict__ txt,
        const float* __restrict__ scale_p, const unsigned short* __restrict__ txtB,
        float* __restrict__ pmax, float* __restrict__ psum,
        float* __restrict__ lval, int* __restrict__ tailcnt,
        float* __restrict__ out) {
    __shared__ unsigned short Ahi[16 * DIM];   // 24 KB, A-frag order
    __shared__ float logitsS[16 * 260];        // 16.6 KB (+4 pad vs bank stride)
    __shared__ int isLast;
    __shared__ float part[16];

    const int tid  = threadIdx.x;
    const int wave = tid >> 6;
    const int lane = tid & 63;
    const int quad = lane >> 4;
    const int l15  = lane & 15;
    const int r0    = (blockIdx.x >> 2) * 16;
    const int chunk = blockIdx.x & 3;

    // stage A: wave w converts img row r0+w into frag order
    {
        const float* ir = img + (size_t)(r0 + wave) * DIM;
#pragma unroll
        for (int j = 0; j < 12; ++j) {
            const int k = lane + j * 64;
            Ahi[((k >> 3) * 16 + wave) * 8 + (k & 7)] = to_bf16(ir[k]);
        }
    }
    __syncthreads();

    // k-loop: wave's global col-tile t, one MFMA per 32-k step; B-frags are
    // contiguous 1 KB runs in txtB (L2-resident) — no k-loop barriers.
    const int t = chunk * 16 + wave;
    const int foff = quad * 128 + l15 * 8;
    f32x4 acc = {0.f, 0.f, 0.f, 0.f};
#pragma unroll
    for (int kk = 0; kk < 24; ++kk) {
        const short8 a = *(const short8*)&Ahi[kk * 512 + foff];
        const short8 b = *(const short8*)(txtB + (size_t)(kk * 64 + t) * 512 + foff);
        acc = __builtin_amdgcn_mfma_f32_16x16x32_bf16(a, b, acc, 0, 0, 0);
    }

    // C layout: col = l15, row = quad*4 + r  [verified, absmax 0.0]
    const float scale = scale_p[0];
#pragma unroll
    for (int r = 0; r < 4; ++r)
        logitsS[(quad * 4 + r) * 260 + wave * 16 + l15] = scale * acc[r];
    __syncthreads();

    // per-row partials: wave w = row w; 4 floats/lane over 256 cols
    {
        const float4 f = *(const float4*)&logitsS[wave * 260 + lane * 4];
        float mx = fmaxf(fmaxf(f.x, f.y), fmaxf(f.z, f.w));
#pragma unroll
        for (int s = 32; s; s >>= 1) mx = fmaxf(mx, __shfl_xor(mx, s, 64));
        float sum = __expf(f.x - mx) + __expf(f.y - mx) +
                    __expf(f.z - mx) + __expf(f.w - mx);
#pragma unroll
        for (int s = 32; s; s >>= 1) sum += __shfl_xor(sum, s, 64);
        if (lane == 0) {
            atomicExch(&pmax[(r0 + wave) * 4 + chunk], mx);
            atomicExch(&psum[(r0 + wave) * 4 + chunk], sum);
        }
    }

    // labels: waves 0..3 handle row j = r0 + chunk*4 + wave.
    // Filter: float2 signature at row start (float compares -> can never
    // exclude a true float== match). Decide: exact float== verify.
    if (wave < 4) {
        const int j = r0 + chunk * 4 + wave;
        const float2 sj = *(const float2*)(img + (size_t)j * DIM);
        int lo = -1;
        int label = j;
        for (;;) {
            int cand = BATCH;
#pragma unroll
            for (int it = 0; it < 16; ++it) {
                const int i = lane + it * 64;          // always < 1024, in-bounds
                const float2 si = *(const float2*)(img + (size_t)i * DIM);
                if (i < j && i > lo && si.x == sj.x && si.y == sj.y)
                    cand = min(cand, i);
            }
#pragma unroll
            for (int s = 32; s; s >>= 1) cand = min(cand, __shfl_xor(cand, s, 64));
            if (cand >= j) break;                      // no candidate -> label = j
            const float4* rpm = (const float4*)(img + (size_t)cand * DIM);
            const float4* rpj = (const float4*)(img + (size_t)j * DIM);
            bool eq = true;
#pragma unroll
            for (int cc = 0; cc < 3; ++cc) {
                float4 vm = rpm[cc * 64 + lane];
                float4 vj = rpj[cc * 64 + lane];
                eq = eq && (vm.x == vj.x) && (vm.y == vj.y) &&
                     (vm.z == vj.z) && (vm.w == vj.w);
            }
            if (__all(eq)) { label = cand; break; }
            lo = cand;                                 // false positive: rescan above it
        }

        // exact fp32 label logit: scale * dot(img[j], txt[label])
        const float4* aj = (const float4*)(img + (size_t)j * DIM);
        const float4* bl = (const float4*)(txt + (size_t)label * DIM);
        float s = 0.0f;
#pragma unroll
        for (int cc = 0; cc < 3; ++cc) {
            const float4 va = aj[cc * 64 + lane];
            const float4 vb = bl[cc * 64 + lane];
            s += va.x * vb.x + va.y * vb.y + va.z * vb.z + va.w * vb.w;
        }
#pragma unroll
        for (int m = 32; m; m >>= 1) s += __shfl_xor(s, m, 64);
        if (lane == 0) atomicExch(&lval[j], scale * s);
    }

    // last-block tail — NO release threadfence (the experiment). The
    // __syncthreads' per-wave vmcnt(0) drain guarantees all data atomics
    // completed at the coherent point before tid0's tailcnt RMW is issued.
    __syncthreads();
    if (tid == 0)
        isLast = (atomicAdd(tailcnt, 1) == (int)gridDim.x - 1) ? 1 : 0;
    __syncthreads();
    if (!isLast) return;
    __threadfence();   // acquire: invalidate local caches before remote reads

    // thread t combines row t: lse from 4 chunk partials minus label logit
    {
        const float4 m4 = *(const float4*)&pmax[tid * 4];
        const float4 s4 = *(const float4*)&psum[tid * 4];
        const float lv = lval[tid];
        const float gmax = fmaxf(fmaxf(m4.x, m4.y), fmaxf(m4.z, m4.w));
        const float ss = s4.x * __expf(m4.x - gmax) + s4.y * __expf(m4.y - gmax)
                       + s4.z * __expf(m4.z - gmax) + s4.w * __expf(m4.w - gmax);
        float loss = gmax + __logf(ss) - lv;
#pragma unroll
        for (int m = 32; m; m >>= 1) loss += __shfl_xor(loss, m, 64);
        if (lane == 0) part[wave] = loss;
        __syncthreads();
        if (tid == 0) {
            float tot = 0.0f;
#pragma unroll
            for (int w = 0; w < 16; ++w) tot += part[w];
            out[0] = tot * (1.0f / BATCH);
        }
    }
}

extern "C" void kernel_launch(void* const* d_in, const int* in_sizes, int n_in,
                              void* d_out, int out_size, void* d_ws, size_t ws_size,
                              hipStream_t stream) {
    const float* img   = (const float*)d_in[0];
    const float* txt   = (const float*)d_in[1];
    const float* scale = (const float*)d_in[2];
    float* out = (float*)d_out;
    char* ws = (char*)d_ws;

    int*   tailcnt = (int*)(ws + WS_TAIL);
    float* pmax    = (float*)(ws + WS_PMAX);
    float* psum    = (float*)(ws + WS_PSUM);
    float* lval    = (float*)(ws + WS_LVAL);
    unsigned short* txtB = (unsigned short*)(ws + WS_TXTB);

    prep_kernel<<<256, 256, 0, stream>>>(txt, tailcnt, txtB);
    gemm_fused<<<256, 1024, 0, stream>>>(img, txt, scale, txtB,
                                         pmax, psum, lval, tailcnt, out);
}